// Round 3
// baseline (971.592 us; speedup 1.0000x reference)
//
#include <hip/hip_runtime.h>
#include <math.h>

#define T_TOK 8192
#define DDIM  1024
#define FDIM  4096
#define NEXP  8
#define MAXTILES 136

typedef __attribute__((ext_vector_type(8))) short short8;
typedef __attribute__((ext_vector_type(4))) float f32x4;
typedef unsigned short u16;
typedef unsigned int   u32;

typedef const __attribute__((address_space(1))) u32* gp_t;
typedef       __attribute__((address_space(3))) u32* lp_t;

__device__ __forceinline__ void gload16(const void* g, void* l) {
  __builtin_amdgcn_global_load_lds((gp_t)g, (lp_t)l, 16, 0, 0);
}

__device__ __forceinline__ u16 f2bf(float f) {
  u32 u = __float_as_uint(f);
  u = u + 0x7FFFu + ((u >> 16) & 1u);
  return (u16)(u >> 16);
}

__device__ __forceinline__ float gelu_exact(float v) {
  return 0.5f * v * (1.0f + erff(v * 0.70710678118654752440f));
}

// bijective XCD chunking (m204)
__device__ __forceinline__ int xcd_swz(int orig, int nwg) {
  int xcd = orig & 7;
  int q = nwg >> 3, r = nwg & 7;
  int base = (xcd < r) ? xcd * (q + 1) : r * (q + 1) + (xcd - r) * q;
  return base + (orig >> 3);
}

// ---------------- router (+ x->bf16 fused): one wave per token ----------------
__global__ __launch_bounds__(256) void router_kernel(
    const float* __restrict__ x, const float* __restrict__ gw,
    const float* __restrict__ gb, u16* __restrict__ xb,
    int* __restrict__ counts, int* __restrict__ sel, float* __restrict__ wts)
{
  const int t    = blockIdx.x * 4 + (threadIdx.x >> 6);
  const int lane = threadIdx.x & 63;
  const float* xr = x + (size_t)t * DDIM;
  u16* xbr = xb + (size_t)t * DDIM;
  float lg[NEXP];
  #pragma unroll
  for (int e = 0; e < NEXP; e++) lg[e] = 0.f;
  #pragma unroll
  for (int i = 0; i < 4; i++) {
    int d0 = i * 256 + lane * 4;
    float4 v = *(const float4*)(xr + d0);
    ushort4 o;
    o.x = f2bf(v.x); o.y = f2bf(v.y); o.z = f2bf(v.z); o.w = f2bf(v.w);
    *(ushort4*)(xbr + d0) = o;
    const float* g = gw + (size_t)d0 * NEXP;
    #pragma unroll
    for (int e = 0; e < NEXP; e++)
      lg[e] += v.x * g[e] + v.y * g[NEXP + e] + v.z * g[2 * NEXP + e] + v.w * g[3 * NEXP + e];
  }
  #pragma unroll
  for (int off = 32; off > 0; off >>= 1) {
    #pragma unroll
    for (int e = 0; e < NEXP; e++) lg[e] += __shfl_down(lg[e], off);
  }
  if (lane == 0) {
    float v0 = -1e30f, v1 = -1e30f; int s0 = 0, s1 = 0;
    #pragma unroll
    for (int e = 0; e < NEXP; e++) {
      float v = lg[e] + gb[e];
      if (v > v0) { v1 = v0; s1 = s0; v0 = v; s0 = e; }
      else if (v > v1) { v1 = v; s1 = e; }
    }
    float a  = expf(v1 - v0);
    float w0 = 1.f / (1.f + a);
    sel[t * 2] = s0; sel[t * 2 + 1] = s1;
    wts[t * 2] = w0; wts[t * 2 + 1] = 1.f - w0;
    atomicAdd(&counts[s0], 1); atomicAdd(&counts[s1], 1);
  }
}

// ---------------- scan + tile map ----------------
__global__ void scan_kernel(const int* __restrict__ counts,
                            int* __restrict__ offsets, int* __restrict__ pos,
                            int* __restrict__ map_e, int* __restrict__ map_r,
                            int* __restrict__ nT)
{
  if (threadIdx.x == 0) {
    int run = 0, nt = 0;
    for (int e = 0; e < NEXP; e++) {
      offsets[e] = run; pos[e] = run;
      int c = counts[e];
      int ntile = (c + 127) >> 7;
      for (int i = 0; i < ntile; i++) { map_e[nt] = e; map_r[nt] = i * 128; nt++; }
      run += c;
    }
    nT[0] = nt;
  }
}

__global__ __launch_bounds__(256) void slot_assign_kernel(
    const int* __restrict__ sel, const float* __restrict__ wts,
    int* __restrict__ pos, int* __restrict__ slot_token,
    float* __restrict__ slot_weight)
{
  const int t = blockIdx.x * 256 + threadIdx.x;
  #pragma unroll
  for (int k = 0; k < 2; k++) {
    int e = sel[t * 2 + k];
    int p = atomicAdd(&pos[e], 1);
    slot_token[p] = t; slot_weight[p] = wts[t * 2 + k];
  }
}

// ---- weight transpose + bf16: in [M][N] f32 -> out [N][M] bf16 ----
// 128(M) x 64(N) tile; stores are 256B-contiguous runs.
__global__ __launch_bounds__(256) void wtrans_kernel(
    const float* __restrict__ in, u16* __restrict__ out, int M, int N)
{
  const int e = blockIdx.z;
  in  += (size_t)e * M * N;
  out += (size_t)e * M * N;
  const int r0 = blockIdx.y * 128;  // M dim
  const int c0 = blockIdx.x * 64;   // N dim
  __shared__ float tile[128][65];
  const int tid = threadIdx.x;
  const int lr = tid >> 4;
  const int lc = (tid & 15) * 4;
  #pragma unroll
  for (int p = 0; p < 8; p++) {
    int r = p * 16 + lr;
    float4 v = *(const float4*)(in + (size_t)(r0 + r) * N + (c0 + lc));
    tile[r][lc] = v.x; tile[r][lc + 1] = v.y; tile[r][lc + 2] = v.z; tile[r][lc + 3] = v.w;
  }
  __syncthreads();
  const int oc = tid >> 4;
  const int om = (tid & 15) * 8;
  #pragma unroll
  for (int p = 0; p < 4; p++) {
    int c = p * 16 + oc;
    short8 o;
    #pragma unroll
    for (int j = 0; j < 8; j++) o[j] = (short)f2bf(tile[om + j][c]);
    *(short8*)(out + (size_t)(c0 + c) * M + (r0 + om)) = o;
  }
}

// ---------------- grouped GEMM1: H = gelu(X@W1 + b1) ----------------
// dbuf LDS, stage-next-first, one barrier per K-step (T3-minimum).
__global__ __launch_bounds__(256) void gemm1_kernel(
    const u16* __restrict__ XB, const u16* __restrict__ W1T,
    const float* __restrict__ B1,
    const int* __restrict__ counts, const int* __restrict__ offsets,
    const int* __restrict__ slot_token,
    const int* __restrict__ map_e, const int* __restrict__ map_r,
    const int* __restrict__ nT, u16* __restrict__ H)
{
  const int gid   = xcd_swz(blockIdx.x, gridDim.x);
  const int n_idx = gid / MAXTILES;
  const int t_idx = gid - n_idx * MAXTILES;
  if (t_idx >= nT[0]) return;
  const int e    = map_e[t_idx];
  const int row0 = map_r[t_idx];
  const int cnt  = counts[e];
  const int off  = offsets[e];
  const int n0   = n_idx * 128;

  __shared__ __align__(16) u16 As[2][128 * 32];
  __shared__ __align__(16) u16 Bs[2][128 * 32];

  const int tid = threadIdx.x, wave = tid >> 6, lane = tid & 63;
  const int ca = wave * 64 + lane;
  const int rA0 = ca >> 2, sl0 = ca & 3;

  int t0 = slot_token[off + row0 + rA0];      if ((u32)t0 >= T_TOK) t0 = 0;
  int t1 = slot_token[off + row0 + rA0 + 64]; if ((u32)t1 >= T_TOK) t1 = 0;
  const char* gA0 = (const char*)XB + (((size_t)t0 * DDIM) + sl0 * 8) * 2;
  const char* gA1 = (const char*)XB + (((size_t)t1 * DDIM) + sl0 * 8) * 2;
  const char* gB0 = (const char*)W1T + (((size_t)(e * FDIM + n0 + rA0)) * DDIM + sl0 * 8) * 2;
  const char* gB1 = (const char*)W1T + (((size_t)(e * FDIM + n0 + rA0 + 64)) * DDIM + sl0 * 8) * 2;

  char* baseA = (char*)As;
  char* baseB = (char*)Bs;
  auto stage = [&](int buf, int k0) {
    char* a = baseA + buf * 8192 + wave * 1024;
    char* b = baseB + buf * 8192 + wave * 1024;
    gload16(gA0 + (size_t)k0 * 2, a);
    gload16(gA1 + (size_t)k0 * 2, a + 4096);
    gload16(gB0 + (size_t)k0 * 2, b);
    gload16(gB1 + (size_t)k0 * 2, b + 4096);
  };

  f32x4 acc[4][4] = {};
  const int wr = wave >> 1, wc = wave & 1;
  const int lr = lane & 15, lk = (lane >> 4) * 8;

  stage(0, 0);
  __syncthreads();
  int cur = 0;
  for (int t = 0; t < DDIM / 32; t++) {
    if (t + 1 < DDIM / 32) stage(cur ^ 1, (t + 1) * 32);
    const u16* Ab = As[cur];
    const u16* Bb = Bs[cur];
    short8 a[4], b[4];
    #pragma unroll
    for (int m = 0; m < 4; m++)
      a[m] = *(const short8*)&Ab[(wr * 64 + m * 16 + lr) * 32 + lk];
    #pragma unroll
    for (int n = 0; n < 4; n++)
      b[n] = *(const short8*)&Bb[(wc * 64 + n * 16 + lr) * 32 + lk];
    #pragma unroll
    for (int m = 0; m < 4; m++)
      #pragma unroll
      for (int n = 0; n < 4; n++)
        acc[m][n] = __builtin_amdgcn_mfma_f32_16x16x32_bf16(a[m], b[n], acc[m][n], 0, 0, 0);
    __syncthreads();
    cur ^= 1;
  }

  #pragma unroll
  for (int nn = 0; nn < 4; nn++) {
    int col = n0 + wc * 64 + nn * 16 + lr;
    float b1v = B1[e * FDIM + col];
    #pragma unroll
    for (int m = 0; m < 4; m++) {
      int rbase = wr * 64 + m * 16 + (lane >> 4) * 4;
      #pragma unroll
      for (int j = 0; j < 4; j++) {
        int r = rbase + j;
        if (row0 + r < cnt) {
          float v = acc[m][nn][j] + b1v;
          H[(size_t)(off + row0 + r) * FDIM + col] = f2bf(gelu_exact(v));
        }
      }
    }
  }
}

// ---------------- grouped GEMM2 + fused combine ----------------
// out[tok] += wgt * (H@W2 + b2), via f32 atomics (exactly 2 adds/element).
__global__ __launch_bounds__(256) void gemm2_kernel(
    const u16* __restrict__ H, const u16* __restrict__ W2T,
    const float* __restrict__ B2,
    const int* __restrict__ counts, const int* __restrict__ offsets,
    const int* __restrict__ slot_token, const float* __restrict__ slot_weight,
    const int* __restrict__ map_e, const int* __restrict__ map_r,
    const int* __restrict__ nT, float* __restrict__ out)
{
  const int gid   = xcd_swz(blockIdx.x, gridDim.x);
  const int n_idx = gid / MAXTILES;
  const int t_idx = gid - n_idx * MAXTILES;
  if (t_idx >= nT[0]) return;
  const int e    = map_e[t_idx];
  const int row0 = map_r[t_idx];
  const int cnt  = counts[e];
  const int off  = offsets[e];
  const int n0   = n_idx * 128;

  __shared__ __align__(16) u16 As[2][128 * 32];
  __shared__ __align__(16) u16 Bs[2][128 * 32];

  const int tid = threadIdx.x, wave = tid >> 6, lane = tid & 63;
  const int ca = wave * 64 + lane;
  const int rA0 = ca >> 2, sl0 = ca & 3;

  const char* gA0 = (const char*)H + ((size_t)(off + row0 + rA0) * FDIM + sl0 * 8) * 2;
  const char* gA1 = (const char*)H + ((size_t)(off + row0 + rA0 + 64) * FDIM + sl0 * 8) * 2;
  const char* gB0 = (const char*)W2T + ((size_t)(e * DDIM + n0 + rA0) * FDIM + sl0 * 8) * 2;
  const char* gB1 = (const char*)W2T + ((size_t)(e * DDIM + n0 + rA0 + 64) * FDIM + sl0 * 8) * 2;

  char* baseA = (char*)As;
  char* baseB = (char*)Bs;
  auto stage = [&](int buf, int k0) {
    char* a = baseA + buf * 8192 + wave * 1024;
    char* b = baseB + buf * 8192 + wave * 1024;
    gload16(gA0 + (size_t)k0 * 2, a);
    gload16(gA1 + (size_t)k0 * 2, a + 4096);
    gload16(gB0 + (size_t)k0 * 2, b);
    gload16(gB1 + (size_t)k0 * 2, b + 4096);
  };

  f32x4 acc[4][4] = {};
  const int wr = wave >> 1, wc = wave & 1;
  const int lr = lane & 15, lk = (lane >> 4) * 8;

  stage(0, 0);
  __syncthreads();
  int cur = 0;
  for (int t = 0; t < FDIM / 32; t++) {
    if (t + 1 < FDIM / 32) stage(cur ^ 1, (t + 1) * 32);
    const u16* Ab = As[cur];
    const u16* Bb = Bs[cur];
    short8 a[4], b[4];
    #pragma unroll
    for (int m = 0; m < 4; m++)
      a[m] = *(const short8*)&Ab[(wr * 64 + m * 16 + lr) * 32 + lk];
    #pragma unroll
    for (int n = 0; n < 4; n++)
      b[n] = *(const short8*)&Bb[(wc * 64 + n * 16 + lr) * 32 + lk];
    #pragma unroll
    for (int m = 0; m < 4; m++)
      #pragma unroll
      for (int n = 0; n < 4; n++)
        acc[m][n] = __builtin_amdgcn_mfma_f32_16x16x32_bf16(a[m], b[n], acc[m][n], 0, 0, 0);
    __syncthreads();
    cur ^= 1;
  }

  #pragma unroll
  for (int m = 0; m < 4; m++) {
    int rbase = wr * 64 + m * 16 + (lane >> 4) * 4;
    #pragma unroll
    for (int j = 0; j < 4; j++) {
      int r = rbase + j;
      if (row0 + r >= cnt) continue;
      size_t s = (size_t)(off + row0 + r);
      int tok = slot_token[s];
      float wgt = slot_weight[s];
      #pragma unroll
      for (int nn = 0; nn < 4; nn++) {
        int col = n0 + wc * 64 + nn * 16 + lr;
        float v = (acc[m][nn][j] + B2[e * DDIM + col]) * wgt;
        atomicAdd(&out[(size_t)tok * DDIM + col], v);
      }
    }
  }
}

extern "C" void kernel_launch(void* const* d_in, const int* in_sizes, int n_in,
                              void* d_out, int out_size, void* d_ws, size_t ws_size,
                              hipStream_t stream)
{
  (void)in_sizes; (void)n_in; (void)ws_size;
  const float* x  = (const float*)d_in[0];
  const float* gw = (const float*)d_in[1];
  const float* gb = (const float*)d_in[2];
  const float* w1 = (const float*)d_in[3];
  const float* b1 = (const float*)d_in[4];
  const float* w2 = (const float*)d_in[5];
  const float* b2 = (const float*)d_in[6];

  char* ws = (char*)d_ws;
  int*   counts = (int*)(ws + 0);
  int*   posp   = (int*)(ws + 64);
  int*   offp   = (int*)(ws + 128);
  int*   nT     = (int*)(ws + 192);
  int*   map_e  = (int*)(ws + 256);
  int*   map_r  = (int*)(ws + 1024);

  size_t p = 2048;
  int*   sel   = (int*)(ws + p);   p += (size_t)T_TOK * 2 * 4;
  float* wts   = (float*)(ws + p); p += (size_t)T_TOK * 2 * 4;
  int*   stok  = (int*)(ws + p);   p += (size_t)(2 * T_TOK + 256) * 4;
  float* swgt  = (float*)(ws + p); p += (size_t)(2 * T_TOK + 256) * 4;
  p = (p + 1048575) & ~(size_t)1048575;
  u16*   xb    = (u16*)(ws + p);   p += (size_t)T_TOK * DDIM * 2;
  u16*   w1t   = (u16*)(ws + p);   p += (size_t)NEXP * DDIM * FDIM * 2;
  u16*   w2t   = (u16*)(ws + p);   p += (size_t)NEXP * DDIM * FDIM * 2;
  u16*   Hbuf  = (u16*)(ws + p);

  hipMemsetAsync(ws, 0, 256, stream);
  hipMemsetAsync(d_out, 0, (size_t)out_size * sizeof(float), stream);
  router_kernel<<<T_TOK / 4, 256, 0, stream>>>(x, gw, gb, xb, counts, sel, wts);
  scan_kernel<<<1, 64, 0, stream>>>(counts, offp, posp, map_e, map_r, nT);
  slot_assign_kernel<<<T_TOK / 256, 256, 0, stream>>>(sel, wts, posp, stok, swgt);
  // W2 first so w1t is cache-warm when gemm1 starts
  wtrans_kernel<<<dim3(DDIM / 64, FDIM / 128, NEXP), 256, 0, stream>>>(w2, w2t, FDIM, DDIM);
  wtrans_kernel<<<dim3(FDIM / 64, DDIM / 128, NEXP), 256, 0, stream>>>(w1, w1t, DDIM, FDIM);

  gemm1_kernel<<<(FDIM / 128) * MAXTILES, 256, 0, stream>>>(
      xb, w1t, b1, counts, offp, stok, map_e, map_r, nT, Hbuf);
  gemm2_kernel<<<(DDIM / 128) * MAXTILES, 256, 0, stream>>>(
      Hbuf, w2t, b2, counts, offp, stok, swgt, map_e, map_r, nT, (float*)d_out);
}